// Round 1
// baseline (2077.090 us; speedup 1.0000x reference)
//
#include <hip/hip_runtime.h>
#include <math.h>

#define WPB 4  // waves (targets) per block

__global__ __launch_bounds__(256)
void copy_x_kernel(const float4* __restrict__ x, float4* __restrict__ out, int n4) {
    int i = blockIdx.x * blockDim.x + threadIdx.x;
    if (i < n4) out[i] = x[i];
}

// One wave per target pixel. lane = output channel c (0..63).
// Softmax trick: logits' feat_px-part + sm_b are constant per segment -> cancel.
// ptx_out[p] = ptx[p]@W1 + q[t],  q[t] = feat_px[t]@W2 + fo_b.
__global__ __launch_bounds__(256)
void fused_kernel(const float* __restrict__ x,
                  const float* __restrict__ ptx,
                  const float* __restrict__ sm_w,
                  const float* __restrict__ fo_w,
                  const float* __restrict__ fo_b,
                  const int* __restrict__ point_key,
                  const int* __restrict__ pixel_tgt_idx,
                  float* __restrict__ xout,
                  float* __restrict__ ptx_out,
                  int n_tgt, int hw)
{
    __shared__ float w1[64 * 64];       // fo_w rows 0..63   (ptx part)
    __shared__ float w2[64 * 64];       // fo_w rows 64..127 (feat_px part)
    __shared__ float smw[64];
    __shared__ float fob[64];
    __shared__ float fpx[WPB][64];
    __shared__ float ptxs[WPB][8 * 64];

    const int tid = threadIdx.x;
    #pragma unroll 4
    for (int i = tid; i < 64 * 64; i += 256) {
        w1[i] = fo_w[i];
        w2[i] = fo_w[4096 + i];
    }
    if (tid < 64) { smw[tid] = sm_w[tid]; fob[tid] = fo_b[tid]; }
    __syncthreads();

    const int wid  = tid >> 6;
    const int lane = tid & 63;

    for (int t0 = blockIdx.x * WPB; t0 < n_tgt; t0 += gridDim.x * WPB) {
        const int t = t0 + wid;
        if (t >= n_tgt) continue;

        const int pix = pixel_tgt_idx[t];
        const int r0  = point_key[t];
        int deg = point_key[t + 1] - r0;
        if (deg > 8) deg = 8;

        // ---- stage to LDS (wave-local; no barrier needed) ----
        fpx[wid][lane] = x[(size_t)lane * hw + pix];
        #pragma unroll
        for (int p = 0; p < 8; ++p)
            ptxs[wid][p * 64 + lane] =
                (p < deg) ? ptx[((size_t)(r0 + p)) * 64 + lane] : 0.0f;

        // ---- q = fo_b + feat_px @ W2  (column `lane`) ----
        float q = fob[lane];
        #pragma unroll
        for (int k4 = 0; k4 < 16; ++k4) {
            const float4 f = *(const float4*)&fpx[wid][k4 * 4];  // uniform b128
            q = fmaf(f.x, w2[(k4 * 4 + 0) * 64 + lane], q);
            q = fmaf(f.y, w2[(k4 * 4 + 1) * 64 + lane], q);
            q = fmaf(f.z, w2[(k4 * 4 + 2) * 64 + lane], q);
            q = fmaf(f.w, w2[(k4 * 4 + 3) * 64 + lane], q);
        }

        // ---- logits (ptx part only; segment-constant part cancels) ----
        float l[8];
        #pragma unroll
        for (int p = 0; p < 8; ++p) {
            float v = ptxs[wid][p * 64 + lane] * smw[lane];
            #pragma unroll
            for (int off = 32; off > 0; off >>= 1) v += __shfl_xor(v, off);
            l[p] = v;  // same value on all 64 lanes
        }

        // ---- segment softmax over deg points ----
        float m = -3.4e38f;
        #pragma unroll
        for (int p = 0; p < 8; ++p) if (p < deg) m = fmaxf(m, l[p]);
        float s = 0.0f, wgt[8];
        #pragma unroll
        for (int p = 0; p < 8; ++p) {
            wgt[p] = (p < deg) ? expf(l[p] - m) : 0.0f;
            s += wgt[p];
        }
        const float inv = 1.0f / (s + 1e-16f);

        // ---- acc[p] = ptx[p] @ W1 (column `lane`); weights reused across 8 points ----
        float acc[8] = {0.f, 0.f, 0.f, 0.f, 0.f, 0.f, 0.f, 0.f};
        #pragma unroll
        for (int k4 = 0; k4 < 16; ++k4) {
            const float wa = w1[(k4 * 4 + 0) * 64 + lane];
            const float wb = w1[(k4 * 4 + 1) * 64 + lane];
            const float wc = w1[(k4 * 4 + 2) * 64 + lane];
            const float wd = w1[(k4 * 4 + 3) * 64 + lane];
            #pragma unroll
            for (int p = 0; p < 8; ++p) {
                const float4 a = *(const float4*)&ptxs[wid][p * 64 + k4 * 4];  // uniform b128
                acc[p] = fmaf(a.x, wa, acc[p]);
                acc[p] = fmaf(a.y, wb, acc[p]);
                acc[p] = fmaf(a.z, wc, acc[p]);
                acc[p] = fmaf(a.w, wd, acc[p]);
            }
        }

        // ---- outputs: ptx_out rows (coalesced) + weighted aggregate ----
        float agg = 0.0f;
        #pragma unroll
        for (int p = 0; p < 8; ++p) {
            if (p < deg) {
                const float po = acc[p] + q;
                ptx_out[((size_t)(r0 + p)) * 64 + lane] = po;
                agg = fmaf(wgt[p] * inv, po, agg);
            }
        }
        xout[(size_t)lane * hw + pix] = agg;  // scatter; lines filled by 16 neighbor targets
    }
}

extern "C" void kernel_launch(void* const* d_in, const int* in_sizes, int n_in,
                              void* d_out, int out_size, void* d_ws, size_t ws_size,
                              hipStream_t stream) {
    const float* x             = (const float*)d_in[0];
    const float* ptx           = (const float*)d_in[1];
    const float* sm_w          = (const float*)d_in[2];
    // d_in[3] = sm_b: segment-constant logit shift, cancels in softmax
    const float* fo_w          = (const float*)d_in[4];
    const float* fo_b          = (const float*)d_in[5];
    const int*   point_key     = (const int*)d_in[6];
    const int*   pixel_tgt_idx = (const int*)d_in[7];

    const int x_elems = in_sizes[0];      // 64 * H * W
    const int hw      = x_elems / 64;
    const int n_tgt   = in_sizes[7];

    float* xout    = (float*)d_out;
    float* ptx_out = xout + (size_t)x_elems;

    const int n4 = x_elems / 4;
    copy_x_kernel<<<(n4 + 255) / 256, 256, 0, stream>>>(
        (const float4*)x, (float4*)xout, n4);

    int blocks = 2048;
    const int needed = (n_tgt + WPB - 1) / WPB;
    if (blocks > needed) blocks = needed;
    fused_kernel<<<blocks, 256, 0, stream>>>(
        x, ptx, sm_w, fo_w, fo_b, point_key, pixel_tgt_idx,
        xout, ptx_out, n_tgt, hw);
}

// Round 2
// 141.406 us; speedup vs baseline: 14.6889x; 14.6889x over previous
//
#include <hip/hip_runtime.h>
#include <hip/hip_bf16.h>
#include <math.h>

typedef __attribute__((ext_vector_type(8))) short short8v;
typedef __attribute__((ext_vector_type(4))) float float4v;

__device__ __forceinline__ short f2bf(float f) {
    __hip_bfloat16 h = __float2bfloat16(f);
    short s;
    __builtin_memcpy(&s, &h, sizeof(short));
    return s;
}

__device__ __forceinline__ float4v mfma_bf16(short8v a, short8v b, float4v c) {
    return __builtin_amdgcn_mfma_f32_16x16x32_bf16(a, b, c, 0, 0, 0);
}

__global__ __launch_bounds__(256)
void copy_x_kernel(const float4* __restrict__ x, float4* __restrict__ out, int n4) {
    int i = blockIdx.x * blockDim.x + threadIdx.x;
    if (i < n4) out[i] = x[i];
}

// Block = 256 threads (4 waves), 32 consecutive targets.
// Softmax: feat_px part + sm_b cancel (segment-constant). logits = ptx @ sm_w[:64],
// computed as column 64 of an 80-wide MFMA B (W1 | smw | 0-pad).
// ptx_out = ptx@W1 + q[t],  q = fpx@W2 + fo_b  (q via MFMA on gathered fpx tile).
__global__ __launch_bounds__(256, 3)
void fused_kernel(const float* __restrict__ x,
                  const float* __restrict__ ptx,
                  const float* __restrict__ sm_w,
                  const float* __restrict__ fo_w,
                  const float* __restrict__ fo_b,
                  const int* __restrict__ point_key,
                  const int* __restrict__ pixel_tgt_idx,
                  float* __restrict__ xout,
                  float* __restrict__ ptx_out,
                  int n_tgt, int n_pts, int hw)
{
    __shared__ unsigned short fpx[32][72];   // bf16 gathered x tile, row=local target (pad->2-way free)
    __shared__ float q_lds[32][68];          // q = fo_b + fpx@W2
    __shared__ float agg_lds[32][68];        // aggregated xout values
    __shared__ int pix_s[32], r0_s[32], deg_s[32];

    const int tid  = threadIdx.x;
    const int lane = tid & 63;
    const int w    = tid >> 6;
    const int t0   = blockIdx.x * 32;
    const int lo16 = lane & 15;
    const int g    = lane >> 4;

    // ---- per-target metadata ----
    if (tid < 32) {
        int t = t0 + tid;
        bool v = t < n_tgt;
        int r0 = v ? point_key[t] : 0;
        int d  = v ? (point_key[t + 1] - r0) : 0;
        pix_s[tid] = v ? pixel_tgt_idx[t] : 0;
        r0_s[tid]  = r0;
        deg_s[tid] = d > 8 ? 8 : d;
    }
    __syncthreads();

    // ---- gather fpx: lane=target (consecutive pix -> coalesced), bf16 to LDS ----
    {
        int tgt = tid & 31, cq = tid >> 5;
        int pix = pix_s[tgt];
        #pragma unroll
        for (int i = 0; i < 8; ++i) {
            int c = cq * 8 + i;
            fpx[tgt][c] = (unsigned short)f2bf(x[(size_t)c * hw + pix]);
        }
    }
    __syncthreads();

    // ---- q-GEMM: C(32x64) = fpx(32x64) @ W2(64x64); wave w: m-tile w&1, coltiles (w>>1)*2+{0,1} ----
    {
        const int mt_q = w & 1;
        const int ctb  = (w >> 1) * 2;
        short8v b2[2][2];
        #pragma unroll
        for (int ci = 0; ci < 2; ++ci)
            #pragma unroll
            for (int kh = 0; kh < 2; ++kh) {
                short8v bb;
                int col = (ctb + ci) * 16 + lo16;
                int kbase = kh * 32 + g * 8;
                #pragma unroll
                for (int j = 0; j < 8; ++j)
                    bb[j] = f2bf(fo_w[(size_t)(64 + kbase + j) * 64 + col]);
                b2[ci][kh] = bb;
            }
        short8v a2[2];
        #pragma unroll
        for (int kh = 0; kh < 2; ++kh) {
            int row = mt_q * 16 + lo16;
            a2[kh] = *(const short8v*)&fpx[row][kh * 32 + g * 8];
        }
        float4v qc0 = {0.f, 0.f, 0.f, 0.f}, qc1 = {0.f, 0.f, 0.f, 0.f};
        qc0 = mfma_bf16(a2[0], b2[0][0], qc0);
        qc0 = mfma_bf16(a2[1], b2[0][1], qc0);
        qc1 = mfma_bf16(a2[0], b2[1][0], qc1);
        qc1 = mfma_bf16(a2[1], b2[1][1], qc1);
        #pragma unroll
        for (int ci = 0; ci < 2; ++ci) {
            int col = (ctb + ci) * 16 + lo16;
            float fb = fo_b[col];
            const float4v& qc = ci ? qc1 : qc0;
            #pragma unroll
            for (int r = 0; r < 4; ++r)
                q_lds[mt_q * 16 + g * 4 + r][col] = qc[r] + fb;
        }
    }

    // ---- B1 fragments: [W1(64 couts) | smw | zeros] -> 5 col-tiles x 2 K-halves ----
    short8v b1[5][2];
    #pragma unroll
    for (int ct = 0; ct < 5; ++ct)
        #pragma unroll
        for (int kh = 0; kh < 2; ++kh) {
            short8v bb;
            int kbase = kh * 32 + g * 8;
            #pragma unroll
            for (int j = 0; j < 8; ++j) {
                int k = kbase + j;
                float f = (ct < 4) ? fo_w[(size_t)k * 64 + ct * 16 + lo16]
                                   : ((lo16 == 0) ? sm_w[k] : 0.0f);
                bb[j] = f2bf(f);
            }
            b1[ct][kh] = bb;
        }
    __syncthreads();   // q_lds ready

    // ---- main loop: wave owns 8 targets = 64 point-slots = 4 m-tiles ----
    const int tw0 = w * 8;
    #pragma unroll
    for (int mt = 0; mt < 4; ++mt) {
        // A: 16 point rows from global ptx (consecutive points -> coalesced)
        int s_row = mt * 16 + lo16;
        int tlA   = tw0 + (s_row >> 3);
        int pg    = r0_s[tlA] + (s_row & 7);
        if (pg >= n_pts) pg = n_pts - 1;
        const float* prow = ptx + (size_t)pg * 64 + g * 8;
        short8v a[2];
        #pragma unroll
        for (int kh = 0; kh < 2; ++kh) {
            float4 f0 = *(const float4*)(prow + kh * 32);
            float4 f1 = *(const float4*)(prow + kh * 32 + 4);
            short8v aa;
            aa[0] = f2bf(f0.x); aa[1] = f2bf(f0.y); aa[2] = f2bf(f0.z); aa[3] = f2bf(f0.w);
            aa[4] = f2bf(f1.x); aa[5] = f2bf(f1.y); aa[6] = f2bf(f1.z); aa[7] = f2bf(f1.w);
            a[kh] = aa;
        }
        float4v c[5];
        #pragma unroll
        for (int ct = 0; ct < 5; ++ct) {
            float4v z = {0.f, 0.f, 0.f, 0.f};
            z = mfma_bf16(a[0], b1[ct][0], z);
            c[ct] = mfma_bf16(a[1], b1[ct][1], z);
        }

        // epilogue: per lane -> target tE, points pE=(g&1)*4+r on rows g*4+r
        const int tE   = tw0 + mt * 2 + (g >> 1);
        const int degE = deg_s[tE];
        const int r0E  = r0_s[tE];
        float lgt[4];
        #pragma unroll
        for (int r = 0; r < 4; ++r) {
            float v = __shfl(c[4][r], lane & 48);   // logit column (col 64) for row g*4+r
            lgt[r] = (((g & 1) * 4 + r) < degE) ? v : -3.4e38f;
        }
        float m4 = fmaxf(fmaxf(lgt[0], lgt[1]), fmaxf(lgt[2], lgt[3]));
        float m8 = fmaxf(m4, __shfl_xor(m4, 16));
        float wgt[4], wsum = 0.f;
        #pragma unroll
        for (int r = 0; r < 4; ++r) {
            int pE = (g & 1) * 4 + r;
            wgt[r] = (pE < degE) ? __expf(lgt[r] - m8) : 0.0f;
            wsum += wgt[r];
        }
        wsum += __shfl_xor(wsum, 16);
        float inv = 1.0f / (wsum + 1e-16f);

        #pragma unroll
        for (int ct = 0; ct < 4; ++ct) {
            int col = ct * 16 + lo16;
            float qv = q_lds[tE][col];
            float ap = 0.f;
            #pragma unroll
            for (int r = 0; r < 4; ++r) {
                float po = c[ct][r] + qv;
                int pE = (g & 1) * 4 + r;
                if (pE < degE)
                    ptx_out[(size_t)(r0E + pE) * 64 + col] = po;
                ap = fmaf(wgt[r] * inv, po, ap);
            }
            ap += __shfl_xor(ap, 16);
            if (!(lane & 16))                 // groups 0,2 hold both targets' sums
                agg_lds[tE][col] = ap;
        }
    }
    __syncthreads();

    // ---- xout write-back: lane=target -> coalesced scatter ----
    {
        int tgt = tid & 31, cq = tid >> 5;
        if (t0 + tgt < n_tgt) {
            int pix = pix_s[tgt];
            #pragma unroll
            for (int i = 0; i < 8; ++i) {
                int c = cq * 8 + i;
                xout[(size_t)c * hw + pix] = agg_lds[tgt][c];
            }
        }
    }
}

extern "C" void kernel_launch(void* const* d_in, const int* in_sizes, int n_in,
                              void* d_out, int out_size, void* d_ws, size_t ws_size,
                              hipStream_t stream) {
    const float* x             = (const float*)d_in[0];
    const float* ptx           = (const float*)d_in[1];
    const float* sm_w          = (const float*)d_in[2];
    // d_in[3] = sm_b: segment-constant logit shift, cancels in softmax
    const float* fo_w          = (const float*)d_in[4];
    const float* fo_b          = (const float*)d_in[5];
    const int*   point_key     = (const int*)d_in[6];
    const int*   pixel_tgt_idx = (const int*)d_in[7];

    const int x_elems = in_sizes[0];          // 64 * H * W
    const int hw      = x_elems / 64;
    const int n_tgt   = in_sizes[7];
    const int n_pts   = in_sizes[1] / 64;

    float* xout    = (float*)d_out;
    float* ptx_out = xout + (size_t)x_elems;

    const int n4 = x_elems / 4;
    copy_x_kernel<<<(n4 + 255) / 256, 256, 0, stream>>>(
        (const float4*)x, (float4*)xout, n4);

    const int blocks = (n_tgt + 31) / 32;
    fused_kernel<<<blocks, 256, 0, stream>>>(
        x, ptx, sm_w, fo_w, fo_b, point_key, pixel_tgt_idx,
        xout, ptx_out, n_tgt, n_pts, hw);
}